// Round 8
// baseline (2924.540 us; speedup 1.0000x reference)
//
#include <hip/hip_runtime.h>

#define B_   64
#define T_   512
#define HID_ 512
#define H_   256
#define G4   1024
#define N2   2048
#define M_   (B_*T_)
#define NL_  9

typedef short short8 __attribute__((ext_vector_type(8)));
typedef float f32x4 __attribute__((ext_vector_type(4)));
typedef _Float16 f16x2 __attribute__((ext_vector_type(2)));
typedef unsigned int u32x2 __attribute__((ext_vector_type(2)));

__device__ inline float bf2f(unsigned short u) {
  unsigned int x = ((unsigned int)u) << 16;
  return __builtin_bit_cast(float, x);
}
__device__ inline unsigned short f2bf(float f) {
  unsigned int u = __builtin_bit_cast(unsigned int, f);
  return (unsigned short)((u + 0x7fffu + ((u >> 16) & 1u)) >> 16);
}
__device__ inline unsigned short f2h(float f) {
  _Float16 h = (_Float16)f;
  return __builtin_bit_cast(unsigned short, h);
}
__device__ inline float fdot2(unsigned int w, unsigned int h, float acc) {
#if __has_builtin(__builtin_amdgcn_fdot2)
  return __builtin_amdgcn_fdot2(__builtin_bit_cast(f16x2, w),
                                __builtin_bit_cast(f16x2, h), acc, false);
#else
  f16x2 a = __builtin_bit_cast(f16x2, w), b = __builtin_bit_cast(f16x2, h);
  return acc + (float)a[0]*(float)b[0] + (float)a[1]*(float)b[1];
#endif
}
__device__ inline float sigm(float x)     { return 1.f / (1.f + __expf(-x)); }
__device__ inline float tanhfast(float x) { return 1.f - 2.f / (__expf(2.f*x) + 1.f); }

// 4-group (16-lane-group) sum across the wave: valid in lanes 0-15 of each wave
// (sum over lane, lane^16, lane^32, lane^48). Pure-VALU via permlane swaps.
__device__ inline float qsum(float x) {
#if __has_builtin(__builtin_amdgcn_permlane32_swap)
  u32x2 r = __builtin_amdgcn_permlane32_swap(
      __builtin_bit_cast(unsigned int, x), __builtin_bit_cast(unsigned int, x),
      false, false);
  x += __builtin_bit_cast(float, r[1]);   // lanes<32: += x[lane+32]
#else
  x += __shfl_xor(x, 32, 64);
#endif
#if __has_builtin(__builtin_amdgcn_permlane16_swap)
  u32x2 s = __builtin_amdgcn_permlane16_swap(
      __builtin_bit_cast(unsigned int, x), __builtin_bit_cast(unsigned int, x),
      false, false);
  x += __builtin_bit_cast(float, s[1]);   // rows0: += x[lane+16]
#else
  x += __shfl_xor(x, 16, 64);
#endif
  return x;
}

// async global->LDS 16B copy (dest must be wave-uniform-base + lane*16)
__device__ inline void gload16(const unsigned short* g, unsigned short* l) {
  __builtin_amdgcn_global_load_lds(
      (const __attribute__((address_space(1))) void*)g,
      (__attribute__((address_space(3))) void*)l, 16, 0, 0);
}

// ---------------- prep kernels ----------------
__global__ void k_cast_bf16x4(const float4* __restrict__ src, ushort4* __restrict__ dst, int n4) {
  int i = blockIdx.x*256 + threadIdx.x;
  if (i < n4) {
    float4 v = src[i];
    ushort4 o;
    o.x = f2bf(v.x); o.y = f2bf(v.y); o.z = f2bf(v.z); o.w = f2bf(v.w);
    dst[i] = o;
  }
}

// w_hh (2,2,1024,256) fp32 -> fp16 pairs, per-thread layout for k_rec (ksplit=4).
// k_rec thread t: wave w=t>>6, lane=t&63, q=lane>>4 (k-quarter), p=lane&15,
//   P=w*16+p -> units {2P, 2P+1}; 8 gate-cols c = unit_sel*4 + gate;
//   col = gate*256 + (2P + unit_sel); k-range [q*64, q*64+64).
// uint4 index per col: j=0..7 covers k-pairs 4j..4j+3 (k0 = q*64 + 8j + 2qq).
// regs: j=0..5 (i4 = c*6+j, 48 u4) -> wr[((ld*48+i4)*512+t)*4+qq]
// LDS : j=6..7 (m  = c*2+(j-6), 16 u4) -> wl[((ld*16+m)*512+t)*4+qq]
__global__ void k_pack_whh(const float* __restrict__ whh, unsigned int* __restrict__ wr,
                           unsigned int* __restrict__ wl) {
  int idx = blockIdx.x*256 + threadIdx.x;           // 524288 total
  int qq  = idx & 3;
  int t   = (idx >> 2) & 511;
  int i4  = (idx >> 11) & 63;
  int ld  = idx >> 17;
  int lane = t & 63, wave = t >> 6;
  int q = lane >> 4, p = lane & 15;
  int P = wave*16 + p;
  int c, j;
  if (i4 < 48) { c = i4/6; j = i4%6; }
  else         { int m = i4-48; c = m>>1; j = 6 + (m&1); }
  int unit_sel = c >> 2, g = c & 3;
  int col = g*256 + 2*P + unit_sel;
  int k0  = q*64 + 8*j + 2*qq;
  const float* src = whh + ((size_t)ld*1024 + col)*256 + k0;
  unsigned int pack = (unsigned int)f2h(src[0]) | ((unsigned int)f2h(src[1]) << 16);
  if (i4 < 48) wr[(((size_t)ld*48 + i4)*512 + t)*4 + qq] = pack;
  else         wl[(((size_t)ld*16 + (i4-48))*512 + t)*4 + qq] = pack;
}

// bias sums stored GATE-INTERLEAVED: bs[l*2048 + d*1024 + u*4 + g]
__global__ void k_bias_sum(const float* __restrict__ bi, const float* __restrict__ bh,
                           float* __restrict__ bs) {
  int i = blockIdx.x*256 + threadIdx.x;
  if (i < 4096) {
    int l = i >> 11, r = i & 2047;
    int dd = r >> 10, nn = r & 1023, g = nn >> 8, u = nn & 255;
    bs[l*2048 + dd*1024 + u*4 + g] = bi[i] + bh[i];
  }
}

__global__ void k_cls_pad(const float* __restrict__ w, unsigned short* __restrict__ dst) {
  int i = blockIdx.x*256 + threadIdx.x;             // 16*512
  if (i < 16*512) {
    int n = i >> 9, k = i & 511;
    dst[i] = (n < NL_) ? f2bf(w[n*512 + k]) : (unsigned short)0;
  }
}

__global__ void k_embed(const int* __restrict__ ids, const float* __restrict__ emb,
                        unsigned short* __restrict__ x0) {
  int idx = blockIdx.x*256 + threadIdx.x;           // M_*128
  int m  = idx >> 7;
  int e4 = (idx & 127) << 2;
  int id = ids[m];
  float4 v = *(const float4*)(emb + (size_t)id*HID_ + e4);
  ushort4 o;
  o.x = f2bf(v.x); o.y = f2bf(v.y); o.z = f2bf(v.z); o.w = f2bf(v.w);
  *(ushort4*)(x0 + (size_t)m*HID_ + e4) = o;
}

// ---------------- input-projection GEMM: 128x128 tile, 2-phase double-buffered LDS --------
// n-block = (dir d, 32-unit range u0). Epilogue packs the 4 gates of one unit into ONE
// coalesced b64 store at gate-interleaved ncol = d*1024 + u*4 + g (k_rec's layout).
__global__ __launch_bounds__(256) void k_gemm_inproj(const unsigned short* __restrict__ A,
    const unsigned short* __restrict__ Bt, const float* __restrict__ bias,
    unsigned short* __restrict__ C) {
  __shared__ unsigned short As[2][4096];   // 2 bufs x (4 kg x 128 rows x 8 elems)
  __shared__ unsigned short Bs[2][4096];
  int tid  = threadIdx.x;
  int lane = tid & 63, w = tid >> 6;
  int wm = w >> 1, wn = w & 1;
  int d  = blockIdx.x >> 3;            // dir
  int u0 = (blockIdx.x & 7) * 32;      // unit range
  int m0 = blockIdx.y * 128;

  int c0 = tid, c1 = 256 + tid;
  int ar0 = c0 & 127, ak0 = c0 >> 7;
  int ar1 = c1 & 127, ak1 = c1 >> 7;
  int br0 = d*1024 + (ar0 >> 5)*256 + u0 + (ar0 & 31);   // strided gate-chunk rows
  int br1 = d*1024 + (ar1 >> 5)*256 + u0 + (ar1 & 31);
  const unsigned short* gA0 = A  + (size_t)(m0 + ar0)*512 + ak0*8;
  const unsigned short* gA1 = A  + (size_t)(m0 + ar1)*512 + ak1*8;
  const unsigned short* gB0 = Bt + (size_t)br0*512 + ak0*8;
  const unsigned short* gB1 = Bt + (size_t)br1*512 + ak1*8;

  int r = lane & 15, kg = lane >> 4;

  f32x4 acc[4][4];
  #pragma unroll
  for (int mi = 0; mi < 4; mi++)
    #pragma unroll
    for (int ni = 0; ni < 4; ni++)
      acc[mi][ni] = (f32x4){0,0,0,0};

  // prologue: stage kt=0 into buf 0
  gload16(gA0, As[0] + c0*8); gload16(gA1, As[0] + c1*8);
  gload16(gB0, Bs[0] + c0*8); gload16(gB1, Bs[0] + c1*8);
  gA0 += 32; gA1 += 32; gB0 += 32; gB1 += 32;
  __syncthreads();

  int cur = 0;
  #pragma unroll 1
  for (int kt = 0; kt < 16; kt++) {
    if (kt < 15) {                     // stage NEXT tile into the other buffer
      unsigned short* nA = As[cur^1];
      unsigned short* nB = Bs[cur^1];
      gload16(gA0, nA + c0*8); gload16(gA1, nA + c1*8);
      gload16(gB0, nB + c0*8); gload16(gB1, nB + c1*8);
      gA0 += 32; gA1 += 32; gB0 += 32; gB1 += 32;
    }
    const short8* Af = (const short8*)As[cur] + (size_t)kg*128 + wm*64 + r;
    const short8* Bf = (const short8*)Bs[cur] + (size_t)kg*128 + wn*16 + r;
    short8 av[4], bv[4];
    #pragma unroll
    for (int i = 0; i < 4; i++) { av[i] = Af[i*16]; bv[i] = Bf[i*32]; }
    #pragma unroll
    for (int mi = 0; mi < 4; mi++)
      #pragma unroll
      for (int ni = 0; ni < 4; ni++)
        acc[mi][ni] = __builtin_amdgcn_mfma_f32_16x16x32_bf16(av[mi], bv[ni], acc[mi][ni], 0, 0, 0);
    __syncthreads();                   // drains next-stage vmcnt AFTER compute + read-fence
    cur ^= 1;
  }

  int rbase = m0 + wm*64 + (lane >> 4)*4;
  int ucol  = u0 + wn*16 + (lane & 15);
  float4 bb = *(const float4*)(bias + (size_t)d*1024 + ucol*4);   // gate-interleaved bias
  #pragma unroll
  for (int mi = 0; mi < 4; mi++)
    #pragma unroll
    for (int rr = 0; rr < 4; rr++) {
      ushort4 o;
      o.x = f2bf(acc[mi][0][rr] + bb.x);
      o.y = f2bf(acc[mi][1][rr] + bb.y);
      o.z = f2bf(acc[mi][2][rr] + bb.z);
      o.w = f2bf(acc[mi][3][rr] + bb.w);
      *(ushort4*)(C + (size_t)(rbase + mi*16 + rr)*N2 + d*1024 + ucol*4) = o;
    }
}

// ---------------- classifier GEMM ----------------
__global__ __launch_bounds__(256) void k_cls(const unsigned short* __restrict__ X,
    const unsigned short* __restrict__ Wb, const float* __restrict__ cb,
    float* __restrict__ out) {
  int lane = threadIdx.x & 63, wave = threadIdx.x >> 6;
  int m0 = blockIdx.x*64 + wave*16;
  int r = lane & 15, kg = lane >> 4;
  const short8* Ap = (const short8*)(X  + (size_t)(m0 + r)*512 + kg*8);
  const short8* Bp = (const short8*)(Wb + (size_t)r*512 + kg*8);
  f32x4 acc = {0,0,0,0};
  #pragma unroll
  for (int kb = 0; kb < 16; kb++)
    acc = __builtin_amdgcn_mfma_f32_16x16x32_bf16(Ap[kb*4], Bp[kb*4], acc, 0, 0, 0);
  int row0 = m0 + (lane >> 4)*4, col = lane & 15;
  if (col < NL_) {
    float bb = cb[col];
    #pragma unroll
    for (int rr = 0; rr < 4; rr++)
      out[(size_t)(row0+rr)*NL_ + col] = acc[rr] + bb;
  }
}

// ---------------- LSTM recurrence: 512 thr, ksplit=4 -------------------------------------
// Thread: q = lane>>4 covers k in [q*64,(q+1)*64); P = wave*16 + (lane&15) -> units 2P,2P+1,
// all 4 gates (8 accumulators). h-broadcast reads HALVED vs ksplit=2: 8 b128/thread
// (per-wave 8 instrs, 4 addrs each, conflict-free via 144-B quarter stride).
// Cross-quarter reduce: permlane32_swap + permlane16_swap (pure VALU).
// Activation in q==0 lanes; h double-buffered in LDS; lgkm-only barrier per step.
#define DOT4(ACC, W0, W1, W2, W3, HH) do { \
  ACC = fdot2(W0, (HH).x, ACC); ACC = fdot2(W1, (HH).y, ACC); \
  ACC = fdot2(W2, (HH).z, ACC); ACC = fdot2(W3, (HH).w, ACC); } while(0)

__global__ __launch_bounds__(512, 2) void k_rec(const unsigned short* __restrict__ xp,
    const uint4* __restrict__ wr, const uint4* __restrict__ wl,
    unsigned short* __restrict__ xout, int layer) {
  extern __shared__ char smem[];
  // [0,131072): swizzled weight tails; [131072,+576): hA; [+576,+576): hB
  char* hAb = smem + 131072;
  char* hBb = hAb + 576;
  int t = threadIdx.x;
  int lane = t & 63, wave = t >> 6;
  int q = lane >> 4, p = lane & 15;
  int P = wave*16 + p;                 // unit pair: units 2P, 2P+1
  int b = blockIdx.x >> 1, d = blockIdx.x & 1;
  int ld = layer*2 + d;

  // per-thread swizzled LDS base: bits 4-6 of byte addr XORed with t bits 3-5
  char* wlb = smem + (((unsigned)(t*16)) ^ (((unsigned)t & 0x38u) << 1));
  {
    const uint4* src = wl + (size_t)ld*16*512 + t;
    #pragma unroll
    for (int m = 0; m < 16; m++)
      *(uint4*)(wlb + m*8192) = src[(size_t)m*512];
  }
  uint4 wq[48];
  {
    const uint4* src = wr + (size_t)ld*48*512 + t;
    #pragma unroll
    for (int i = 0; i < 48; i++) wq[i] = src[(size_t)i*512];
  }
  if (t < 144) ((unsigned int*)hAb)[t] = 0u;   // zero initial h (576 B)
  float cst0 = 0.f, cst1 = 0.f;
  // x prefetch: 8 bf16 (2 units x 4 gates), gate-interleaved layout
  const unsigned short* xbase = xp + (size_t)b*T_*N2 + (size_t)d*G4 + P*8;
  unsigned short* obase = xout + (size_t)b*T_*HID_ + d*H_ + 2*P;
  // h write offset (units 2P,2P+1 share one u32): 144-B quarter stride
  int hwoff = ((2*P) >> 6)*144 + ((2*P) & 63)*2;
  __syncthreads();

  int tt = d ? (T_-1) : 0;
  uint4 nx = *(const uint4*)(xbase + (size_t)tt*N2);
  #pragma unroll 1
  for (int step = 0; step < T_; step++) {
    int ttn = d ? (T_-2-step) : (step+1);
    int ttc = (step < T_-1) ? ttn : tt;          // clamp on last step
    uint4 cx = nx;
    nx = *(const uint4*)(xbase + (size_t)ttc*N2);     // early issue
    const char* hb = ((step & 1) ? hBb : hAb) + q*144;
    float a0=0.f,a1=0.f,a2=0.f,a3=0.f,a4=0.f,a5=0.f,a6=0.f,a7=0.f;
    #pragma unroll
    for (int j = 0; j < 6; j++) {      // register-resident k-pair chunks 0..5
      uint4 hh = *(const uint4*)(hb + j*16);
      DOT4(a0, wq[j].x,    wq[j].y,    wq[j].z,    wq[j].w,    hh);
      DOT4(a1, wq[6+j].x,  wq[6+j].y,  wq[6+j].z,  wq[6+j].w,  hh);
      DOT4(a2, wq[12+j].x, wq[12+j].y, wq[12+j].z, wq[12+j].w, hh);
      DOT4(a3, wq[18+j].x, wq[18+j].y, wq[18+j].z, wq[18+j].w, hh);
      DOT4(a4, wq[24+j].x, wq[24+j].y, wq[24+j].z, wq[24+j].w, hh);
      DOT4(a5, wq[30+j].x, wq[30+j].y, wq[30+j].z, wq[30+j].w, hh);
      DOT4(a6, wq[36+j].x, wq[36+j].y, wq[36+j].z, wq[36+j].w, hh);
      DOT4(a7, wq[42+j].x, wq[42+j].y, wq[42+j].z, wq[42+j].w, hh);
    }
    #pragma unroll
    for (int jj = 0; jj < 2; jj++) {   // LDS-resident chunks 6..7
      uint4 hh = *(const uint4*)(hb + (6+jj)*16);
      uint4 q0 = *(const uint4*)(wlb + (0*2+jj)*8192);
      uint4 q1 = *(const uint4*)(wlb + (1*2+jj)*8192);
      uint4 q2 = *(const uint4*)(wlb + (2*2+jj)*8192);
      uint4 q3 = *(const uint4*)(wlb + (3*2+jj)*8192);
      uint4 q4 = *(const uint4*)(wlb + (4*2+jj)*8192);
      uint4 q5 = *(const uint4*)(wlb + (5*2+jj)*8192);
      uint4 q6 = *(const uint4*)(wlb + (6*2+jj)*8192);
      uint4 q7 = *(const uint4*)(wlb + (7*2+jj)*8192);
      DOT4(a0, q0.x, q0.y, q0.z, q0.w, hh);
      DOT4(a1, q1.x, q1.y, q1.z, q1.w, hh);
      DOT4(a2, q2.x, q2.y, q2.z, q2.w, hh);
      DOT4(a3, q3.x, q3.y, q3.z, q3.w, hh);
      DOT4(a4, q4.x, q4.y, q4.z, q4.w, hh);
      DOT4(a5, q5.x, q5.y, q5.z, q5.w, hh);
      DOT4(a6, q6.x, q6.y, q6.z, q6.w, hh);
      DOT4(a7, q7.x, q7.y, q7.z, q7.w, hh);
    }
    a0 = qsum(a0); a1 = qsum(a1); a2 = qsum(a2); a3 = qsum(a3);
    a4 = qsum(a4); a5 = qsum(a5); a6 = qsum(a6); a7 = qsum(a7);
    if (q == 0) {                      // activation: 2 units per lane (lanes 0-15)
      float gi0 = sigm(a0 + bf2f((unsigned short)(cx.x & 0xffff)));
      float gf0 = sigm(a1 + bf2f((unsigned short)(cx.x >> 16)));
      float gg0 = tanhfast(a2 + bf2f((unsigned short)(cx.y & 0xffff)));
      float go0 = sigm(a3 + bf2f((unsigned short)(cx.y >> 16)));
      cst0 = gf0*cst0 + gi0*gg0;
      float h0 = go0 * tanhfast(cst0);
      float gi1 = sigm(a4 + bf2f((unsigned short)(cx.z & 0xffff)));
      float gf1 = sigm(a5 + bf2f((unsigned short)(cx.z >> 16)));
      float gg1 = tanhfast(a6 + bf2f((unsigned short)(cx.w & 0xffff)));
      float go1 = sigm(a7 + bf2f((unsigned short)(cx.w >> 16)));
      cst1 = gf1*cst1 + gi1*gg1;
      float h1 = go1 * tanhfast(cst1);
      char* hn = (step & 1) ? hAb : hBb;
      unsigned int hp = (unsigned int)__builtin_bit_cast(unsigned short, (_Float16)h0)
                      | ((unsigned int)__builtin_bit_cast(unsigned short, (_Float16)h1) << 16);
      *(unsigned int*)(hn + hwoff) = hp;
      unsigned int ob = (unsigned int)f2bf(h0) | ((unsigned int)f2bf(h1) << 16);
      *(unsigned int*)(obase + (size_t)tt*HID_) = ob;
    }
    // LDS-only fence + raw barrier: global store / prefetch stay in flight
    asm volatile("s_waitcnt lgkmcnt(0)" ::: "memory");
    __builtin_amdgcn_s_barrier();
    tt = ttn;
  }
}

// ---------------- CRF ----------------
__global__ void k_zero(float* out) { if (threadIdx.x == 0) out[0] = 0.f; }

__global__ void k_crf(const float* __restrict__ logits, const int* __restrict__ labels,
                      const float* __restrict__ st, const float* __restrict__ et,
                      const float* __restrict__ tr, float* __restrict__ out) {
  int b = blockIdx.x, lane = threadIdx.x;
  bool act = lane < NL_;
  const float* lb = logits + (size_t)b*T_*NL_;
  float trc[9];
  #pragma unroll
  for (int i = 0; i < 9; i++) trc[i] = act ? tr[i*9 + lane] : 0.f;
  float em = act ? lb[lane] : -1e30f;
  float alpha = act ? (st[lane] + em) : -1e30f;
  int prev = labels[b*T_];
  float num = __shfl(alpha, prev);
  for (int ttt = 1; ttt < T_; ttt++) {
    em = act ? lb[ttt*NL_ + lane] : -1e30f;
    float vv[9]; float mx = -1e30f;
    #pragma unroll
    for (int i = 0; i < 9; i++) { vv[i] = __shfl(alpha, i) + trc[i]; mx = fmaxf(mx, vv[i]); }
    float s = 0.f;
    #pragma unroll
    for (int i = 0; i < 9; i++) s += __expf(vv[i] - mx);
    alpha = act ? (mx + __logf(s) + em) : -1e30f;
    int tag = labels[b*T_ + ttt];
    float emtag = __shfl(em, tag);
    if (lane == 0) num += tr[prev*9 + tag] + emtag;
    prev = tag;
  }
  float fa = act ? (alpha + et[lane]) : -1e30f;
  float mx = -1e30f;
  #pragma unroll
  for (int i = 0; i < 9; i++) mx = fmaxf(mx, __shfl(fa, i));
  float s = 0.f;
  #pragma unroll
  for (int i = 0; i < 9; i++) s += __expf(__shfl(fa, i) - mx);
  float denom = mx + __logf(s);
  if (lane == 0) {
    num += et[prev];
    atomicAdd(out, denom - num);
  }
}

// ---------------- launch ----------------
extern "C" void kernel_launch(void* const* d_in, const int* in_sizes, int n_in,
                              void* d_out, int out_size, void* d_ws, size_t ws_size,
                              hipStream_t stream) {
  const int*   ids    = (const int*)d_in[0];
  const int*   labels = (const int*)d_in[1];
  const float* emb    = (const float*)d_in[2];
  const float* w_ih   = (const float*)d_in[3];
  const float* w_hh   = (const float*)d_in[4];
  const float* b_ih   = (const float*)d_in[5];
  const float* b_hh   = (const float*)d_in[6];
  const float* cls_w  = (const float*)d_in[7];
  const float* cls_b  = (const float*)d_in[8];
  const float* st     = (const float*)d_in[9];
  const float* et     = (const float*)d_in[10];
  const float* tr     = (const float*)d_in[11];
  float* out = (float*)d_out;

  char* ws = (char*)d_ws;
  unsigned short* xp    = (unsigned short*)(ws);                  // 134,217,728
  unsigned short* x0    = (unsigned short*)(ws + 134217728);      //  33,554,432
  unsigned short* x1    = (unsigned short*)(ws + 167772160);      //  33,554,432
  unsigned short* wbi   = (unsigned short*)(ws + 201326592);      //   4,194,304
  unsigned int*   wreg  = (unsigned int*)  (ws + 205520896);      //   1,572,864 (48 u4 x 512 t x 4 ld)
  unsigned int*   wldsg = (unsigned int*)  (ws + 207093760);      //     524,288 (16 u4 x 512 t x 4 ld)
  float*          bsum  = (float*)         (ws + 207618048);      //      16,384 (gate-interleaved)
  unsigned short* clswb = (unsigned short*)(ws + 207634432);      //      16,384
  float*          logit = (float*)         (ws + 207650816);      //   1,179,648

  const int REC_SMEM = 131072 + 1280;   // swizzled weight tails + 2x 576B h buffers
  hipFuncSetAttribute((const void*)k_rec, hipFuncAttributeMaxDynamicSharedMemorySize, REC_SMEM);

  k_cast_bf16x4<<<2048, 256, 0, stream>>>((const float4*)w_ih, (ushort4*)wbi, 2*N2*512/4);
  k_pack_whh <<<2048, 256, 0, stream>>>(w_hh, wreg, wldsg);
  k_bias_sum <<<16,   256, 0, stream>>>(b_ih, b_hh, bsum);
  k_cls_pad  <<<32,   256, 0, stream>>>(cls_w, clswb);
  k_embed    <<<16384,256, 0, stream>>>(ids, emb, x0);

  dim3 ggrid(16, 256);   // (2 dirs x 8 unit-blocks), M/128
  k_gemm_inproj<<<ggrid, 256, 0, stream>>>(x0, wbi, bsum, xp);
  k_rec<<<128, 512, REC_SMEM, stream>>>(xp, (const uint4*)wreg, (const uint4*)wldsg, x1, 0);
  k_gemm_inproj<<<ggrid, 256, 0, stream>>>(x1, wbi + (size_t)N2*512, bsum + 2048, xp);
  k_rec<<<128, 512, REC_SMEM, stream>>>(xp, (const uint4*)wreg, (const uint4*)wldsg, x0, 1);
  k_cls<<<512, 256, 0, stream>>>(x0, clswb, cls_b, logit);
  k_zero<<<1, 64, 0, stream>>>(out);
  k_crf<<<64, 64, 0, stream>>>(logit, labels, st, et, tr, out);
}

// Round 9
// 2292.780 us; speedup vs baseline: 1.2755x; 1.2755x over previous
//
#include <hip/hip_runtime.h>

#define B_   64
#define T_   512
#define HID_ 512
#define H_   256
#define G4   1024
#define N2   2048
#define M_   (B_*T_)
#define NL_  9

typedef short short8 __attribute__((ext_vector_type(8)));
typedef float f32x4 __attribute__((ext_vector_type(4)));
typedef _Float16 f16x2 __attribute__((ext_vector_type(2)));
typedef unsigned int u32x2 __attribute__((ext_vector_type(2)));

__device__ inline float bf2f(unsigned short u) {
  unsigned int x = ((unsigned int)u) << 16;
  return __builtin_bit_cast(float, x);
}
__device__ inline unsigned short f2bf(float f) {
  unsigned int u = __builtin_bit_cast(unsigned int, f);
  return (unsigned short)((u + 0x7fffu + ((u >> 16) & 1u)) >> 16);
}
__device__ inline unsigned short f2h(float f) {
  _Float16 h = (_Float16)f;
  return __builtin_bit_cast(unsigned short, h);
}
__device__ inline float fdot2(unsigned int w, unsigned int h, float acc) {
#if __has_builtin(__builtin_amdgcn_fdot2)
  return __builtin_amdgcn_fdot2(__builtin_bit_cast(f16x2, w),
                                __builtin_bit_cast(f16x2, h), acc, false);
#else
  f16x2 a = __builtin_bit_cast(f16x2, w), b = __builtin_bit_cast(f16x2, h);
  return acc + (float)a[0]*(float)b[0] + (float)a[1]*(float)b[1];
#endif
}
__device__ inline float sigm(float x)     { return 1.f / (1.f + __expf(-x)); }
__device__ inline float tanhfast(float x) { return 1.f - 2.f / (__expf(2.f*x) + 1.f); }

// sum of this lane's value with lane^32's value (valid in all lanes): VALU path
__device__ inline float xhalf_sum(float x) {
#if __has_builtin(__builtin_amdgcn_permlane32_swap)
  u32x2 r = __builtin_amdgcn_permlane32_swap(
      __builtin_bit_cast(unsigned int, x), __builtin_bit_cast(unsigned int, x),
      false, false);
  return x + __builtin_bit_cast(float, r[1]);
#else
  return x + __shfl_xor(x, 32, 64);
#endif
}

// async global->LDS 16B copy (dest must be wave-uniform-base + lane*16)
__device__ inline void gload16(const unsigned short* g, unsigned short* l) {
  __builtin_amdgcn_global_load_lds(
      (const __attribute__((address_space(1))) void*)g,
      (__attribute__((address_space(3))) void*)l, 16, 0, 0);
}

// ---------------- prep kernels ----------------
__global__ void k_cast_bf16x4(const float4* __restrict__ src, ushort4* __restrict__ dst, int n4) {
  int i = blockIdx.x*256 + threadIdx.x;
  if (i < n4) {
    float4 v = src[i];
    ushort4 o;
    o.x = f2bf(v.x); o.y = f2bf(v.y); o.z = f2bf(v.z); o.w = f2bf(v.w);
    dst[i] = o;
  }
}

// w_hh (2,2,1024,256) fp32 -> fp16 pairs, per-thread layout for k_rec (ksplit=2).
// thread t: wave=t>>6, lane=t&63, u=wave*32+(lane&31), kh=lane>>5, cols c=g*256+u.
// reg part  (i4=0..47, g=i4/12, j=i4%12): uint q of uint4 -> k0 = kh*128 + 8j + 2q
// lds part  (m=0..15,  g=m>>2, jl=m&3):   uint q of uint4 -> k0 = kh*128 + 96 + 8jl + 2q
__global__ void k_pack_whh(const float* __restrict__ whh, unsigned int* __restrict__ wr,
                           unsigned int* __restrict__ wl) {
  int idx = blockIdx.x*256 + threadIdx.x;           // 524288 total
  int q   = idx & 3;
  int t   = (idx >> 2) & 511;
  int i4  = (idx >> 11) & 63;
  int ld  = idx >> 17;
  int lane = t & 63, wave = t >> 6;
  int u  = wave*32 + (lane & 31);
  int kh = lane >> 5;
  int g, k0;
  if (i4 < 48) { g = i4/12; int j = i4%12; k0 = kh*128 + 8*j + 2*q; }
  else         { int m = i4-48; g = m>>2; int jl = m&3; k0 = kh*128 + 96 + 8*jl + 2*q; }
  int c = g*256 + u;
  const float* src = whh + ((size_t)ld*1024 + c)*256 + k0;
  unsigned int pack = (unsigned int)f2h(src[0]) | ((unsigned int)f2h(src[1]) << 16);
  if (i4 < 48) wr[(((size_t)ld*48 + i4)*512 + t)*4 + q] = pack;
  else         wl[(((size_t)ld*16 + (i4-48))*512 + t)*4 + q] = pack;
}

// bias sums stored GATE-INTERLEAVED: bs[l*2048 + d*1024 + u*4 + g]
__global__ void k_bias_sum(const float* __restrict__ bi, const float* __restrict__ bh,
                           float* __restrict__ bs) {
  int i = blockIdx.x*256 + threadIdx.x;
  if (i < 4096) {
    int l = i >> 11, r = i & 2047;
    int dd = r >> 10, nn = r & 1023, g = nn >> 8, u = nn & 255;
    bs[l*2048 + dd*1024 + u*4 + g] = bi[i] + bh[i];
  }
}

__global__ void k_cls_pad(const float* __restrict__ w, unsigned short* __restrict__ dst) {
  int i = blockIdx.x*256 + threadIdx.x;             // 16*512
  if (i < 16*512) {
    int n = i >> 9, k = i & 511;
    dst[i] = (n < NL_) ? f2bf(w[n*512 + k]) : (unsigned short)0;
  }
}

__global__ void k_embed(const int* __restrict__ ids, const float* __restrict__ emb,
                        unsigned short* __restrict__ x0) {
  int idx = blockIdx.x*256 + threadIdx.x;           // M_*128
  int m  = idx >> 7;
  int e4 = (idx & 127) << 2;
  int id = ids[m];
  float4 v = *(const float4*)(emb + (size_t)id*HID_ + e4);
  ushort4 o;
  o.x = f2bf(v.x); o.y = f2bf(v.y); o.z = f2bf(v.z); o.w = f2bf(v.w);
  *(ushort4*)(x0 + (size_t)m*HID_ + e4) = o;
}

// ---------------- input-projection GEMM: 128x128 tile, 2-phase double-buffered LDS --------
// n-block = (dir d, 32-unit range u0). Epilogue packs the 4 gates of one unit into ONE
// coalesced b64 store at gate-interleaved ncol = d*1024 + u*4 + g (k_rec's layout).
__global__ __launch_bounds__(256) void k_gemm_inproj(const unsigned short* __restrict__ A,
    const unsigned short* __restrict__ Bt, const float* __restrict__ bias,
    unsigned short* __restrict__ C) {
  __shared__ unsigned short As[2][4096];   // 2 bufs x (4 kg x 128 rows x 8 elems)
  __shared__ unsigned short Bs[2][4096];
  int tid  = threadIdx.x;
  int lane = tid & 63, w = tid >> 6;
  int wm = w >> 1, wn = w & 1;
  int d  = blockIdx.x >> 3;            // dir
  int u0 = (blockIdx.x & 7) * 32;      // unit range
  int m0 = blockIdx.y * 128;

  int c0 = tid, c1 = 256 + tid;
  int ar0 = c0 & 127, ak0 = c0 >> 7;
  int ar1 = c1 & 127, ak1 = c1 >> 7;
  int br0 = d*1024 + (ar0 >> 5)*256 + u0 + (ar0 & 31);   // strided gate-chunk rows
  int br1 = d*1024 + (ar1 >> 5)*256 + u0 + (ar1 & 31);
  const unsigned short* gA0 = A  + (size_t)(m0 + ar0)*512 + ak0*8;
  const unsigned short* gA1 = A  + (size_t)(m0 + ar1)*512 + ak1*8;
  const unsigned short* gB0 = Bt + (size_t)br0*512 + ak0*8;
  const unsigned short* gB1 = Bt + (size_t)br1*512 + ak1*8;

  int r = lane & 15, kg = lane >> 4;

  f32x4 acc[4][4];
  #pragma unroll
  for (int mi = 0; mi < 4; mi++)
    #pragma unroll
    for (int ni = 0; ni < 4; ni++)
      acc[mi][ni] = (f32x4){0,0,0,0};

  // prologue: stage kt=0 into buf 0
  gload16(gA0, As[0] + c0*8); gload16(gA1, As[0] + c1*8);
  gload16(gB0, Bs[0] + c0*8); gload16(gB1, Bs[0] + c1*8);
  gA0 += 32; gA1 += 32; gB0 += 32; gB1 += 32;
  __syncthreads();

  int cur = 0;
  #pragma unroll 1
  for (int kt = 0; kt < 16; kt++) {
    if (kt < 15) {                     // stage NEXT tile into the other buffer
      unsigned short* nA = As[cur^1];
      unsigned short* nB = Bs[cur^1];
      gload16(gA0, nA + c0*8); gload16(gA1, nA + c1*8);
      gload16(gB0, nB + c0*8); gload16(gB1, nB + c1*8);
      gA0 += 32; gA1 += 32; gB0 += 32; gB1 += 32;
    }
    const short8* Af = (const short8*)As[cur] + (size_t)kg*128 + wm*64 + r;
    const short8* Bf = (const short8*)Bs[cur] + (size_t)kg*128 + wn*16 + r;
    short8 av[4], bv[4];
    #pragma unroll
    for (int i = 0; i < 4; i++) { av[i] = Af[i*16]; bv[i] = Bf[i*32]; }
    #pragma unroll
    for (int mi = 0; mi < 4; mi++)
      #pragma unroll
      for (int ni = 0; ni < 4; ni++)
        acc[mi][ni] = __builtin_amdgcn_mfma_f32_16x16x32_bf16(av[mi], bv[ni], acc[mi][ni], 0, 0, 0);
    __syncthreads();                   // drains next-stage vmcnt AFTER compute + read-fence
    cur ^= 1;
  }

  int rbase = m0 + wm*64 + (lane >> 4)*4;
  int ucol  = u0 + wn*16 + (lane & 15);
  float4 bb = *(const float4*)(bias + (size_t)d*1024 + ucol*4);   // gate-interleaved bias
  #pragma unroll
  for (int mi = 0; mi < 4; mi++)
    #pragma unroll
    for (int rr = 0; rr < 4; rr++) {
      ushort4 o;
      o.x = f2bf(acc[mi][0][rr] + bb.x);
      o.y = f2bf(acc[mi][1][rr] + bb.y);
      o.z = f2bf(acc[mi][2][rr] + bb.z);
      o.w = f2bf(acc[mi][3][rr] + bb.w);
      *(ushort4*)(C + (size_t)(rbase + mi*16 + rr)*N2 + d*1024 + ucol*4) = o;
    }
}

// ---------------- classifier GEMM ----------------
__global__ __launch_bounds__(256) void k_cls(const unsigned short* __restrict__ X,
    const unsigned short* __restrict__ Wb, const float* __restrict__ cb,
    float* __restrict__ out) {
  int lane = threadIdx.x & 63, wave = threadIdx.x >> 6;
  int m0 = blockIdx.x*64 + wave*16;
  int r = lane & 15, kg = lane >> 4;
  const short8* Ap = (const short8*)(X  + (size_t)(m0 + r)*512 + kg*8);
  const short8* Bp = (const short8*)(Wb + (size_t)r*512 + kg*8);
  f32x4 acc = {0,0,0,0};
  #pragma unroll
  for (int kb = 0; kb < 16; kb++)
    acc = __builtin_amdgcn_mfma_f32_16x16x32_bf16(Ap[kb*4], Bp[kb*4], acc, 0, 0, 0);
  int row0 = m0 + (lane >> 4)*4, col = lane & 15;
  if (col < NL_) {
    float bb = cb[col];
    #pragma unroll
    for (int rr = 0; rr < 4; rr++)
      out[(size_t)(row0+rr)*NL_ + col] = acc[rr] + bb;
  }
}

// ---------------- LSTM recurrence: 512 thr, ksplit=2, 4 gate-cols of 1 unit per thread ----
// (proven r4/r6 structure; LDS-tail dot block moved FIRST so its 8 ds_read_b128 issue
// right after the barrier and their latency overlaps the register-resident dot chunks)
#define DOT4(ACC, W0, W1, W2, W3, HH) do { \
  ACC = fdot2(W0, (HH).x, ACC); ACC = fdot2(W1, (HH).y, ACC); \
  ACC = fdot2(W2, (HH).z, ACC); ACC = fdot2(W3, (HH).w, ACC); } while(0)

__global__ __launch_bounds__(512, 2) void k_rec(const unsigned short* __restrict__ xp,
    const uint4* __restrict__ wr, const uint4* __restrict__ wl,
    unsigned short* __restrict__ xout, int layer) {
  extern __shared__ char smem[];
  // [0,131072): swizzled per-thread weight tails; [131072,+512): hA; [+512,+512): hB
  unsigned int* hA = (unsigned int*)(smem + 131072);
  unsigned int* hB = hA + 128;
  int t = threadIdx.x;
  int lane = t & 63, wave = t >> 6;
  int u  = wave*32 + (lane & 31);
  int kh = lane >> 5;
  bool lo = (lane < 32);
  int b = blockIdx.x >> 1, d = blockIdx.x & 1;
  int ld = layer*2 + d;

  // per-thread swizzled LDS base: bits 4-6 of byte addr XORed with t bits 3-5
  char* wlb = smem + (((unsigned)(t*16)) ^ (((unsigned)t & 0x38u) << 1));
  {
    const uint4* src = wl + (size_t)ld*16*512 + t;
    #pragma unroll
    for (int m = 0; m < 16; m++)
      *(uint4*)(wlb + m*8192) = src[(size_t)m*512];
  }
  uint4 wq[48];
  {
    const uint4* src = wr + (size_t)ld*48*512 + t;
    #pragma unroll
    for (int i = 0; i < 48; i++) wq[i] = src[(size_t)i*512];
  }
  if (t < 128) hA[t] = 0u;
  float cst = 0.f;
  const unsigned short* xbase = xp + (size_t)b*T_*N2 + (size_t)d*G4 + u*4;  // gate-interleaved
  unsigned short* obase = xout + (size_t)b*T_*HID_ + d*H_ + u;
  __syncthreads();

  int tt = d ? (T_-1) : 0;
  ushort4 nx = *(const ushort4*)(xbase + (size_t)tt*N2);
  #pragma unroll 1
  for (int step = 0; step < T_; step++) {
    int ttn = d ? (T_-2-step) : (step+1);
    int ttc = (step < T_-1) ? ttn : tt;          // clamp on last step (harmless reload)
    ushort4 cx = nx;
    nx = *(const ushort4*)(xbase + (size_t)ttc*N2);   // early issue, all lanes
    const uint4* hs = (const uint4*)((step & 1) ? hB : hA) + kh*16;
    float a0 = lo ? bf2f(cx.x) : 0.f;
    float a1 = lo ? bf2f(cx.y) : 0.f;
    float a2 = lo ? bf2f(cx.z) : 0.f;
    float a3 = lo ? bf2f(cx.w) : 0.f;
    #pragma unroll
    for (int jl = 0; jl < 4; jl++) {   // LDS-resident k-pairs 48..63 FIRST (early ds_read issue)
      uint4 hh = hs[12 + jl];
      uint4 q0 = *(const uint4*)(wlb + (0*4+jl)*8192);
      uint4 q1 = *(const uint4*)(wlb + (1*4+jl)*8192);
      uint4 q2 = *(const uint4*)(wlb + (2*4+jl)*8192);
      uint4 q3 = *(const uint4*)(wlb + (3*4+jl)*8192);
      DOT4(a0, q0.x, q0.y, q0.z, q0.w, hh);
      DOT4(a1, q1.x, q1.y, q1.z, q1.w, hh);
      DOT4(a2, q2.x, q2.y, q2.z, q2.w, hh);
      DOT4(a3, q3.x, q3.y, q3.z, q3.w, hh);
    }
    #pragma unroll
    for (int j = 0; j < 12; j++) {     // register-resident k-pairs 0..47
      uint4 hh = hs[j];
      DOT4(a0, wq[j].x,    wq[j].y,    wq[j].z,    wq[j].w,    hh);
      DOT4(a1, wq[12+j].x, wq[12+j].y, wq[12+j].z, wq[12+j].w, hh);
      DOT4(a2, wq[24+j].x, wq[24+j].y, wq[24+j].z, wq[24+j].w, hh);
      DOT4(a3, wq[36+j].x, wq[36+j].y, wq[36+j].z, wq[36+j].w, hh);
    }
    a0 = xhalf_sum(a0); a1 = xhalf_sum(a1);
    a2 = xhalf_sum(a2); a3 = xhalf_sum(a3);
    if (lo) {                          // totals valid in lanes<32
      float gi = sigm(a0);
      float gf = sigm(a1);
      float gg = tanhfast(a2);
      float go = sigm(a3);
      cst = gf*cst + gi*gg;
      float h = go * tanhfast(cst);
      _Float16* hn = (_Float16*)((step & 1) ? hA : hB);
      hn[u] = (_Float16)h;
      obase[(size_t)tt*HID_] = f2bf(h);
    }
    // LDS-only fence + raw barrier: global store / prefetch stay in flight
    asm volatile("s_waitcnt lgkmcnt(0)" ::: "memory");
    __builtin_amdgcn_s_barrier();
    tt = ttn;
  }
}

// ---------------- CRF ----------------
__global__ void k_zero(float* out) { if (threadIdx.x == 0) out[0] = 0.f; }

__global__ void k_crf(const float* __restrict__ logits, const int* __restrict__ labels,
                      const float* __restrict__ st, const float* __restrict__ et,
                      const float* __restrict__ tr, float* __restrict__ out) {
  int b = blockIdx.x, lane = threadIdx.x;
  bool act = lane < NL_;
  const float* lb = logits + (size_t)b*T_*NL_;
  float trc[9];
  #pragma unroll
  for (int i = 0; i < 9; i++) trc[i] = act ? tr[i*9 + lane] : 0.f;
  float em = act ? lb[lane] : -1e30f;
  float alpha = act ? (st[lane] + em) : -1e30f;
  int prev = labels[b*T_];
  float num = __shfl(alpha, prev);
  for (int ttt = 1; ttt < T_; ttt++) {
    em = act ? lb[ttt*NL_ + lane] : -1e30f;
    float vv[9]; float mx = -1e30f;
    #pragma unroll
    for (int i = 0; i < 9; i++) { vv[i] = __shfl(alpha, i) + trc[i]; mx = fmaxf(mx, vv[i]); }
    float s = 0.f;
    #pragma unroll
    for (int i = 0; i < 9; i++) s += __expf(vv[i] - mx);
    alpha = act ? (mx + __logf(s) + em) : -1e30f;
    int tag = labels[b*T_ + ttt];
    float emtag = __shfl(em, tag);
    if (lane == 0) num += tr[prev*9 + tag] + emtag;
    prev = tag;
  }
  float fa = act ? (alpha + et[lane]) : -1e30f;
  float mx = -1e30f;
  #pragma unroll
  for (int i = 0; i < 9; i++) mx = fmaxf(mx, __shfl(fa, i));
  float s = 0.f;
  #pragma unroll
  for (int i = 0; i < 9; i++) s += __expf(__shfl(fa, i) - mx);
  float denom = mx + __logf(s);
  if (lane == 0) {
    num += et[prev];
    atomicAdd(out, denom - num);
  }
}

// ---------------- launch ----------------
extern "C" void kernel_launch(void* const* d_in, const int* in_sizes, int n_in,
                              void* d_out, int out_size, void* d_ws, size_t ws_size,
                              hipStream_t stream) {
  const int*   ids    = (const int*)d_in[0];
  const int*   labels = (const int*)d_in[1];
  const float* emb    = (const float*)d_in[2];
  const float* w_ih   = (const float*)d_in[3];
  const float* w_hh   = (const float*)d_in[4];
  const float* b_ih   = (const float*)d_in[5];
  const float* b_hh   = (const float*)d_in[6];
  const float* cls_w  = (const float*)d_in[7];
  const float* cls_b  = (const float*)d_in[8];
  const float* st     = (const float*)d_in[9];
  const float* et     = (const float*)d_in[10];
  const float* tr     = (const float*)d_in[11];
  float* out = (float*)d_out;

  char* ws = (char*)d_ws;
  unsigned short* xp    = (unsigned short*)(ws);                  // 134,217,728
  unsigned short* x0    = (unsigned short*)(ws + 134217728);      //  33,554,432
  unsigned short* x1    = (unsigned short*)(ws + 167772160);      //  33,554,432
  unsigned short* wbi   = (unsigned short*)(ws + 201326592);      //   4,194,304
  unsigned int*   wreg  = (unsigned int*)  (ws + 205520896);      //   1,572,864 (48 u4 x 512 t x 4 ld)
  unsigned int*   wldsg = (unsigned int*)  (ws + 207093760);      //     524,288 (16 u4 x 512 t x 4 ld)
  float*          bsum  = (float*)         (ws + 207618048);      //      16,384 (gate-interleaved)
  unsigned short* clswb = (unsigned short*)(ws + 207634432);      //      16,384
  float*          logit = (float*)         (ws + 207650816);      //   1,179,648

  const int REC_SMEM = 131072 + 1024;   // swizzled weight tails + h double-buffer
  hipFuncSetAttribute((const void*)k_rec, hipFuncAttributeMaxDynamicSharedMemorySize, REC_SMEM);

  k_cast_bf16x4<<<2048, 256, 0, stream>>>((const float4*)w_ih, (ushort4*)wbi, 2*N2*512/4);
  k_pack_whh <<<2048, 256, 0, stream>>>(w_hh, wreg, wldsg);
  k_bias_sum <<<16,   256, 0, stream>>>(b_ih, b_hh, bsum);
  k_cls_pad  <<<32,   256, 0, stream>>>(cls_w, clswb);
  k_embed    <<<16384,256, 0, stream>>>(ids, emb, x0);

  dim3 ggrid(16, 256);   // (2 dirs x 8 unit-blocks), M/128
  k_gemm_inproj<<<ggrid, 256, 0, stream>>>(x0, wbi, bsum, xp);
  k_rec<<<128, 512, REC_SMEM, stream>>>(xp, (const uint4*)wreg, (const uint4*)wldsg, x1, 0);
  k_gemm_inproj<<<ggrid, 256, 0, stream>>>(x1, wbi + (size_t)N2*512, bsum + 2048, xp);
  k_rec<<<128, 512, REC_SMEM, stream>>>(xp, (const uint4*)wreg, (const uint4*)wldsg, x0, 1);
  k_cls<<<512, 256, 0, stream>>>(x0, clswb, cls_b, logit);
  k_zero<<<1, 64, 0, stream>>>(out);
  k_crf<<<64, 64, 0, stream>>>(logit, labels, st, et, tr, out);
}